// Round 3
// baseline (349114.087 us; speedup 1.0000x reference)
//
#include <hip/hip_runtime.h>
#include <math.h>

#define NLS    4096   // 512 nodes * 8 stalk dims
#define NNODE  512
#define SDIM   8
#define KNN_K  5
#define MAXNBR 128
#define DIN    768
#define NB     32     // panel width

struct Ptrs {
  float* X;      // [2][NNODE][SDIM]
  int*   nn;     // [2][NNODE][KNN_K]
  int*   nbr;    // [2][NNODE][MAXNBR]
  int*   cnt;    // [2][NNODE]
  float* y;      // [2][2][NLS]  symv accumulator, double-buffered by column parity
  float* acol;   // [2][NLS]     corrected column for the CURRENT column k (valid r>=k)
  float* vtw;    // [2][NLS]     v^T y accumulators (zeroed at start)
  float* xn2;    // [2][NLS]     xnorm2 accumulators per column (zeroed at start)
  float* darr;   // [2][NLS]
  float* ebuf;   // [2][NLS]
  float* bta;    // [2][NLS]
  float* e2;     // [2][NLS]
  float* bounds; // [2][2]
  float* eigs;   // [2][NLS]
  float* Vt;     // [2][NB][NLS]
  float* Wt;     // [2][NB][NLS]
  float* c1;     // [2][NB]
  float* c2;     // [2][NB]
  int*   bar;    // [2][NLS][2]  grid-barrier counters (zeroed at start)
  int*   uctr;   // [2][128]     kupd last-WG counters (zeroed at start)
  float* A0;
  float* A1;
};

__device__ __forceinline__ float* matA(const Ptrs& p, int cloud) {
  return cloud == 0 ? p.A0 : p.A1;
}

// single-use grid barrier (counter pre-zeroed). Requires all gridDim.x WGs
// of this z-slice co-resident (enforced via __launch_bounds__ + G<=448).
__device__ __forceinline__ void gbar(int* ctr, int total) {
  __syncthreads();
  if (threadIdx.x == 0) {
    __threadfence();
    atomicAdd(ctr, 1);
    while (atomicAdd(ctr, 0) < total) __builtin_amdgcn_s_sleep(8);
    __threadfence();
  }
  __syncthreads();
}

// ---------------- zero helper ----------------
__global__ void zero_kernel(float* ptr, long n) {
  long i = (long)blockIdx.x * 256 + threadIdx.x;
  if (i < n) ptr[i] = 0.f;
}

// ---------------- projection: X = emb @ W^T ----------------
__global__ void proj_kernel(Ptrs p, const float* q, const float* pe,
                            const float* ne, const float* W) {
  int idx = blockIdx.x * 256 + threadIdx.x;
  if (idx >= 2 * NNODE * SDIM) return;
  int cloud = idx >> 12;
  int rem   = idx & 4095;
  int node  = rem >> 3, t = rem & 7;
  const float* src = (node < 256) ? (q + (size_t)node * DIN)
                                  : ((cloud == 0 ? pe : ne) + (size_t)(node - 256) * DIN);
  const float* wr = W + (size_t)t * DIN;
  float acc = 0.f;
  for (int i = 0; i < DIN; ++i) acc += src[i] * wr[i];
  p.X[(cloud * NNODE + node) * SDIM + t] = acc;
}

// ---------------- KNN ----------------
__global__ void knn_kernel(Ptrs p) {
  int i = blockIdx.x, cloud = blockIdx.z;
  int lane = threadIdx.x;
  __shared__ float d2s[NNODE];
  const float* X = p.X + cloud * NNODE * SDIM;
  float xi[SDIM];
  for (int t = 0; t < SDIM; ++t) xi[t] = X[i * SDIM + t];
  for (int j = lane; j < NNODE; j += 64) {
    float s = 0.f;
    for (int t = 0; t < SDIM; ++t) { float d = xi[t] - X[j * SDIM + t]; s += d * d; }
    d2s[j] = (j == i) ? 3.4e38f : s;
  }
  __syncthreads();
  for (int r = 0; r < KNN_K; ++r) {
    float bv = 3.39e38f; int bi = NNODE;
    for (int j = lane; j < NNODE; j += 64) {
      float val = d2s[j];
      if (val < bv || (val == bv && j < bi)) { bv = val; bi = j; }
    }
    for (int o = 32; o > 0; o >>= 1) {
      float ov = __shfl_down(bv, o); int oi = __shfl_down(bi, o);
      if (ov < bv || (ov == bv && oi < bi)) { bv = ov; bi = oi; }
    }
    if (lane == 0) {
      p.nn[(cloud * NNODE + i) * KNN_K + r] = bi;
      d2s[bi] = 3.4e38f;
    }
    __syncthreads();
  }
}

// ---------------- symmetrized adjacency ----------------
__global__ void adj_kernel(Ptrs p) {
  int idx = blockIdx.x * 256 + threadIdx.x;
  if (idx >= 2 * NNODE) return;
  int cloud = idx >> 9, i = idx & 511;
  const int* nn = p.nn + cloud * NNODE * KNN_K;
  int c = 0;
  for (int j = 0; j < NNODE; ++j) {
    if (j == i) continue;
    bool e = false;
    for (int r = 0; r < KNN_K; ++r)
      if (nn[i * KNN_K + r] == j || nn[j * KNN_K + r] == i) e = true;
    if (e) { if (c < MAXNBR) p.nbr[(cloud * NNODE + i) * MAXNBR + c] = j; ++c; }
  }
  p.cnt[cloud * NNODE + i] = (c > MAXNBR ? MAXNBR : c);
}

// ---------------- dense assembly of L (full square) ----------------
__global__ void assemble_kernel(Ptrs p, int cloud0) {
  int i = blockIdx.x;
  int cloud = cloud0 + blockIdx.z;
  float* A = matA(p, cloud);
  const float* X = p.X + cloud * NNODE * SDIM;
  const int* nbr = p.nbr + (cloud * NNODE + i) * MAXNBR;
  int cnt = p.cnt[cloud * NNODE + i];
  int tid = threadIdx.x;

  for (int idx = tid; idx < SDIM * NLS; idx += 256) {
    int t = idx >> 12;
    int c = idx & 4095;
    A[(size_t)(i * SDIM + t) * NLS + c] = 0.f;
  }
  __shared__ float diag[64];
  __shared__ float xi[SDIM];
  if (tid < SDIM) xi[tid] = X[i * SDIM + tid];
  if (tid < 64)   diag[tid] = 0.f;
  __syncthreads();

  for (int s = 0; s < cnt; ++s) {
    int j = nbr[s];
    float d[SDIM], ss = 0.f;
    for (int t = 0; t < SDIM; ++t) { d[t] = X[j * SDIM + t] - xi[t]; ss += d[t] * d[t]; }
    float dn = sqrtf(ss) + 1e-12f;
    float alpha = dn < 1.f ? dn : 1.f;
    float inv = 1.f / dn;
    if (tid < 64) {
      int t = tid >> 3, t2 = tid & 7;
      float ut = d[t] * inv, ut2 = d[t2] * inv;
      A[(size_t)(i * SDIM + t) * NLS + j * SDIM + t2] =
          alpha * ut * ut2 - (t == t2 ? 1.f : 0.f);
      if (j < i) {
        float beta = 2.f * alpha - alpha * alpha;
        diag[tid] += beta * ut * ut2;
      }
    }
  }
  __syncthreads();
  if (tid < 64) {
    int t = tid >> 3, t2 = tid & 7;
    A[(size_t)(i * SDIM + t) * NLS + i * SDIM + t2] =
        (t == t2 ? (float)cnt : 0.f) - diag[tid];
  }
}

// ---------------- initial column prep (column 0) ----------------
__global__ void ka0_kernel(Ptrs p, int cloud0) {
  int cloud = cloud0 + blockIdx.z;
  const float* A = matA(p, cloud);
  float* acol = p.acol + (size_t)cloud * NLS;
  int tid = threadIdx.x;
  float* y0 = p.y + (size_t)cloud * 2 * NLS;
  for (int r = tid; r < 2 * NLS; r += 256) y0[r] = 0.f;
  float part = 0.f;
  for (int r = tid; r < NLS; r += 256) {
    float a = A[(size_t)r * NLS];       // column 0 (lower)
    acol[r] = a;
    if (r >= 2) part += a * a;
  }
  __shared__ float red[4];
  for (int o = 32; o > 0; o >>= 1) part += __shfl_down(part, o);
  if ((tid & 63) == 0) red[tid >> 6] = part;
  __syncthreads();
  if (tid == 0) p.xn2[cloud * NLS] = red[0] + red[1] + red[2] + red[3];
}

// ---------------- fused per-column kernel ----------------
// phase 1: y = A_sym(lower) * v  (v derived from acol/xn2), c1/c2 dots
// barrier; phase 2a: vty partials; barrier; phase 2b: w, V/W write,
// next-column acol + xnorm2, zero next-parity y.
__global__ __launch_bounds__(256, 4) void col_kernel(Ptrs p, int k, int j, int cloud0) {
  int cloud = cloud0 + blockIdx.z;
  float* A  = matA(p, cloud);
  float* Vt = p.Vt + (size_t)cloud * NB * NLS;
  float* Wt = p.Wt + (size_t)cloud * NB * NLS;
  float* y     = p.y + ((size_t)cloud * 2 + (k & 1)) * NLS;
  float* ynext = p.y + ((size_t)cloud * 2 + ((k + 1) & 1)) * NLS;
  float* acol = p.acol + (size_t)cloud * NLS;
  int* bar = p.bar + ((size_t)cloud * NLS + k) * 2;
  int tid = threadIdx.x, lane = tid & 63, wv = tid >> 6;
  const int s = k + 1, m = NLS - s;
  const int Bt = (m + 127) >> 7;
  const int ntiles = (Bt * (Bt + 1)) >> 1;

  __shared__ float vI[128], vJ[128], colred[512];
  __shared__ float c1s[NB], c2s[NB], vks[NB], wks[NB];
  __shared__ float red4[4];

  // ---- preamble: Householder scalars for this column (redundant per WG) ----
  float xnorm2 = p.xn2[cloud * NLS + k];
  float alpha  = acol[s];
  float beta, tau, scale;
  if (xnorm2 > 0.f) {
    beta  = -copysignf(sqrtf(alpha * alpha + xnorm2), alpha);
    tau   = (beta - alpha) / beta;
    scale = 1.f / (alpha - beta);
  } else { beta = alpha; tau = 0.f; scale = 0.f; }
  if (blockIdx.x == 0 && tid == 0) {
    p.darr[cloud * NLS + k] = acol[k];
    p.ebuf[cloud * NLS + k] = beta;
    p.bta [cloud * NLS + k] = tau;
  }

  // ---- phase 1 ----
  int nwork = ntiles + j;
  for (int it = blockIdx.x; it < nwork; it += gridDim.x) {
    __syncthreads();
    if (it < ntiles) {
      int bi = (int)((sqrtf(8.f * (float)it + 1.f) - 1.f) * 0.5f);
      while (((bi + 1) * (bi + 2)) / 2 <= it) ++bi;
      while ((bi * (bi + 1)) / 2 > it) --bi;
      int bj = it - (bi * (bi + 1)) / 2;
      int r0 = s + (bi << 7), c0 = s + (bj << 7);
      if (tid < 128) {
        int gr = r0 + tid;
        vI[tid] = (gr < NLS) ? ((gr == s) ? 1.f : acol[gr] * scale) : 0.f;
      } else {
        int gc = c0 + tid - 128;
        vJ[tid - 128] = (gc < NLS) ? ((gc == s) ? 1.f : acol[gc] * scale) : 0.f;
      }
      __syncthreads();
      bool dg = (bi == bj);
      float ca0 = 0.f, ca1 = 0.f;
      for (int rl = wv * 32; rl < wv * 32 + 32; ++rl) {
        int gr = r0 + rl;
        int gc0 = c0 + lane, gc1 = c0 + lane + 64;
        float a0 = 0.f, a1 = 0.f;
        if (gr < NLS) {
          const float* Ar = A + (size_t)gr * NLS;
          if (gc0 < NLS && (!dg || gc0 <= gr)) a0 = Ar[gc0];
          if (gc1 < NLS && (!dg || gc1 <= gr)) a1 = Ar[gc1];
        }
        float rp = a0 * vJ[lane] + a1 * vJ[lane + 64];
        for (int o = 32; o > 0; o >>= 1) rp += __shfl_down(rp, o);
        if (lane == 0 && gr < NLS) atomicAdd(&y[gr], rp);
        float vr = vI[rl];
        if (gc0 < gr) ca0 += a0 * vr;
        if (gc1 < gr) ca1 += a1 * vr;
      }
      colred[(wv << 7) + lane] = ca0;
      colred[(wv << 7) + lane + 64] = ca1;
      __syncthreads();
      if (tid < 128) {
        float sum = colred[tid] + colred[128 + tid] + colred[256 + tid] + colred[384 + tid];
        int gc = c0 + tid;
        if (gc < NLS && sum != 0.f) atomicAdd(&y[gc], sum);
      }
    } else {
      int j2 = it - ntiles;
      float s1 = 0.f, s2 = 0.f;
      for (int r = s + tid; r < NLS; r += 256) {
        float v = (r == s) ? 1.f : acol[r] * scale;
        s1 += Wt[(size_t)j2 * NLS + r] * v;
        s2 += Vt[(size_t)j2 * NLS + r] * v;
      }
      for (int o = 32; o > 0; o >>= 1) { s1 += __shfl_down(s1, o); s2 += __shfl_down(s2, o); }
      if (lane == 0) { colred[wv] = s1; colred[4 + wv] = s2; }
      __syncthreads();
      if (tid == 0) {
        p.c1[cloud * NB + j2] = colred[0] + colred[1] + colred[2] + colred[3];
        p.c2[cloud * NB + j2] = colred[4] + colred[5] + colred[6] + colred[7];
      }
    }
  }
  gbar(bar + 0, gridDim.x);

  // ---- phase 2a: vty partials ----
  {
    float pv = 0.f;
    for (int r = s + (blockIdx.x << 8) + tid; r < NLS; r += (gridDim.x << 8)) {
      float v = (r == s) ? 1.f : acol[r] * scale;
      pv += v * y[r];
    }
    for (int o = 32; o > 0; o >>= 1) pv += __shfl_down(pv, o);
    if (lane == 0) red4[wv] = pv;
    __syncthreads();
    if (tid == 0) {
      float t = red4[0] + red4[1] + red4[2] + red4[3];
      if (t != 0.f) atomicAdd(&p.vtw[cloud * NLS + k], t);
    }
    __syncthreads();
  }
  gbar(bar + 1, gridDim.x);

  // ---- phase 2b ----
  if (tid < j) {
    c1s[tid] = p.c1[cloud * NB + tid];
    c2s[tid] = p.c2[cloud * NB + tid];
    vks[tid] = Vt[(size_t)tid * NLS + s];
    wks[tid] = Wt[(size_t)tid * NLS + s];
  }
  __syncthreads();
  float vty = p.vtw[cloud * NLS + k];
  float dotc = 0.f, corrs = 0.f;
  for (int j2 = 0; j2 < j; ++j2) {
    dotc  += c1s[j2] * c2s[j2];
    corrs += vks[j2] * c1s[j2] + wks[j2] * c2s[j2];
  }
  float s2v = tau * (vty - 2.f * dotc);
  float wfirst = tau * y[s] - tau * corrs - 0.5f * tau * s2v;
  bool havenext = (j < NB - 1);
  float xpart = 0.f;
  for (int r = s + (blockIdx.x << 8) + tid; r < NLS; r += (gridDim.x << 8)) {
    float vr = (r == s) ? 1.f : acol[r] * scale;
    float yr = y[r];
    float corr = 0.f, ac2 = 0.f;
    for (int j2 = 0; j2 < j; ++j2) {
      float vj = Vt[(size_t)j2 * NLS + r], wj = Wt[(size_t)j2 * NLS + r];
      corr += vj * c1s[j2] + wj * c2s[j2];
      ac2  += vj * wks[j2] + wj * vks[j2];
    }
    float wr = tau * yr - tau * corr - 0.5f * tau * s2v * vr;
    Vt[(size_t)j * NLS + r] = vr;
    Wt[(size_t)j * NLS + r] = wr;
    ynext[r] = 0.f;
    if (havenext) {
      float ac = A[(size_t)r * NLS + s] - ac2 - (vr * wfirst + wr);
      acol[r] = ac;
      if (r >= s + 2) xpart += ac * ac;
    }
  }
  if (havenext) {
    for (int o = 32; o > 0; o >>= 1) xpart += __shfl_down(xpart, o);
    if (lane == 0) red4[wv] = xpart;
    __syncthreads();
    if (tid == 0) {
      float t = red4[0] + red4[1] + red4[2] + red4[3];
      if (t != 0.f) atomicAdd(&p.xn2[cloud * NLS + k + 1], t);
    }
  }
}

// ---------------- KUPD: lower-triangle rank-2*NB update + next-panel col prep ----------------
__global__ void kupd_kernel(Ptrs p, int k0, int cloud0, int doka, int pidx) {
  int cloud = cloud0 + blockIdx.z;
  float* A = matA(p, cloud);
  const float* Vt = p.Vt + (size_t)cloud * NB * NLS;
  const float* Wt = p.Wt + (size_t)cloud * NB * NLS;
  int base = k0 + NB;
  int tid = threadIdx.x;
  __shared__ float Vr[NB][64], Wr[NB][64], Vc[NB][64], Wc[NB][64];
  __shared__ int lastFlag;
  __shared__ float red[4];

  if (blockIdx.y >= blockIdx.x) {     // lower-triangle tiles only
    int r0 = base + blockIdx.y * 64, c0 = base + blockIdx.x * 64;
    for (int idx = tid; idx < NB * 64; idx += 256) {
      int jj = idx >> 6, i = idx & 63;
      int r = r0 + i, c = c0 + i;
      Vr[jj][i] = (r < NLS) ? Vt[(size_t)jj * NLS + r] : 0.f;
      Wr[jj][i] = (r < NLS) ? Wt[(size_t)jj * NLS + r] : 0.f;
      Vc[jj][i] = (c < NLS) ? Vt[(size_t)jj * NLS + c] : 0.f;
      Wc[jj][i] = (c < NLS) ? Wt[(size_t)jj * NLS + c] : 0.f;
    }
    __syncthreads();
    int ty = tid >> 4, tx = tid & 15;
    float acc[4][4] = {{0.f}};
    for (int jj = 0; jj < NB; ++jj) {
      float vr[4], wr[4], vc[4], wc[4];
      for (int a = 0; a < 4; ++a) {
        vr[a] = Vr[jj][ty * 4 + a]; wr[a] = Wr[jj][ty * 4 + a];
        vc[a] = Vc[jj][tx * 4 + a]; wc[a] = Wc[jj][tx * 4 + a];
      }
      for (int a = 0; a < 4; ++a)
        for (int b = 0; b < 4; ++b)
          acc[a][b] += vr[a] * wc[b] + wr[a] * vc[b];
    }
    for (int a = 0; a < 4; ++a) {
      int r = r0 + ty * 4 + a;
      int c = c0 + tx * 4;
      if (r < NLS && c < NLS) {
        float4* pa = (float4*)&A[(size_t)r * NLS + c];
        float4 old = *pa;
        old.x -= acc[a][0]; old.y -= acc[a][1];
        old.z -= acc[a][2]; old.w -= acc[a][3];
        *pa = old;
      }
    }
  }

  // last-WG: prepare first column of next panel
  if (tid == 0) {
    __threadfence();
    int tot = gridDim.x * gridDim.y;
    int old = atomicAdd(&p.uctr[cloud * 128 + pidx], 1);
    lastFlag = (old == tot - 1) ? 1 : 0;
  }
  __syncthreads();
  if (lastFlag && doka) {
    __threadfence();
    int kn = k0 + NB;
    float* acol = p.acol + (size_t)cloud * NLS;
    float part = 0.f;
    for (int r = kn + tid; r < NLS; r += 256) {
      float a = A[(size_t)r * NLS + kn];   // column kn (lower)
      acol[r] = a;
      if (r >= kn + 2) part += a * a;
    }
    for (int o = 32; o > 0; o >>= 1) part += __shfl_down(part, o);
    if ((tid & 63) == 0) red[tid >> 6] = part;
    __syncthreads();
    if (tid == 0) p.xn2[cloud * NLS + kn] = red[0] + red[1] + red[2] + red[3];
  }
}

// ---------------- trailing 64x64 block: in-LDS tridiagonalization ----------------
__global__ void ktrail_kernel(Ptrs p, int cloud0) {
  int cloud = cloud0 + blockIdx.z;
  float* A = matA(p, cloud);
  const int base = NLS - 64;
  int lane = threadIdx.x;  // 64 threads
  __shared__ float B[64][65];
  __shared__ float vv[64], ww[64];
  for (int r = 0; r < 64; ++r)
    B[r][lane] = (lane <= r) ? A[(size_t)(base + r) * NLS + base + lane]
                             : A[(size_t)(base + lane) * NLS + base + r];
  __syncthreads();
  for (int kl = 0; kl <= 61; ++kl) {
    float val = (lane >= kl + 2) ? B[kl][lane] : 0.f;
    float part = val * val;
    for (int o = 32; o > 0; o >>= 1) part += __shfl_xor(part, o);
    float xnorm2 = part;
    float alpha = B[kl][kl + 1];
    float beta, tau, scale;
    if (xnorm2 > 0.f) {
      beta  = -copysignf(sqrtf(alpha * alpha + xnorm2), alpha);
      tau   = (beta - alpha) / beta;
      scale = 1.f / (alpha - beta);
    } else { beta = alpha; tau = 0.f; scale = 0.f; }
    if (lane == 0) {
      p.darr[cloud * NLS + base + kl] = B[kl][kl];
      p.ebuf[cloud * NLS + base + kl] = beta;
    }
    vv[lane] = (lane == kl + 1) ? 1.f : ((lane >= kl + 2) ? B[kl][lane] * scale : 0.f);
    __syncthreads();
    float yv = 0.f;
    if (lane >= kl + 1)
      for (int c = kl + 1; c < 64; ++c) yv += B[lane][c] * vv[c];
    float vy = (lane >= kl + 1) ? vv[lane] * yv : 0.f;
    for (int o = 32; o > 0; o >>= 1) vy += __shfl_xor(vy, o);
    float w = tau * yv - 0.5f * tau * (tau * vy) * vv[lane];
    ww[lane] = (lane >= kl + 1) ? w : 0.f;
    __syncthreads();
    if (lane >= kl + 1) {
      float vr = vv[lane], wr = ww[lane];
      for (int c = kl + 1; c < 64; ++c)
        B[lane][c] -= vr * ww[c] + wr * vv[c];
    }
    __syncthreads();
  }
  if (lane == 0) {
    p.darr[cloud * NLS + base + 62] = B[62][62];
    p.darr[cloud * NLS + base + 63] = B[63][63];
    p.ebuf[cloud * NLS + base + 62] = B[63][62];
    p.ebuf[cloud * NLS + base + 63] = 0.f;
  }
}

// ---------------- gather tridiagonal + Gershgorin bounds ----------------
__global__ void gather_kernel(Ptrs p, int cloud0) {
  int cloud = cloud0 + blockIdx.z;
  const int n = NLS;
  int tid = threadIdx.x;   // 1024
  const float* d = p.darr + cloud * NLS;
  float* e2 = p.e2 + cloud * NLS;
  __shared__ float elds[NLS];
  for (int i = tid; i < n; i += 1024) {
    float e = (i < n - 1) ? p.ebuf[cloud * NLS + i] : 0.f;
    e2[i]   = e * e;
    elds[i] = fabsf(e);
  }
  __syncthreads();
  float lo = 3.4e38f, hi = -3.4e38f;
  for (int i = tid; i < n; i += 1024) {
    float rad = elds[i] + (i > 0 ? elds[i - 1] : 0.f);
    lo = fminf(lo, d[i] - rad);
    hi = fmaxf(hi, d[i] + rad);
  }
  __shared__ float rl[16], rh[16];
  int lane = tid & 63, wv = tid >> 6;
  for (int o = 32; o > 0; o >>= 1) {
    lo = fminf(lo, __shfl_down(lo, o));
    hi = fmaxf(hi, __shfl_down(hi, o));
  }
  if (lane == 0) { rl[wv] = lo; rh[wv] = hi; }
  __syncthreads();
  if (tid == 0) {
    for (int t = 1; t < 16; ++t) { lo = fminf(lo, rl[t]); hi = fmaxf(hi, rh[t]); }
    p.bounds[cloud * 2 + 0] = lo - 0.5f;
    p.bounds[cloud * 2 + 1] = hi + 0.5f;
  }
}

// ---------------- bisection ----------------
__global__ void bisect_kernel(Ptrs p, int cloud0) {
  int cloud = cloud0 + blockIdx.z;
  int idx = blockIdx.x * 256 + threadIdx.x;
  const float* d  = p.darr + cloud * NLS;
  const float* e2 = p.e2   + cloud * NLS;
  float lo = p.bounds[cloud * 2 + 0];
  float hi = p.bounds[cloud * 2 + 1];
  const float pivmin = 1e-28f;
  for (int it = 0; it < 34; ++it) {
    float mid = 0.5f * (lo + hi);
    int cnt = 0;
    float qq = d[0] - mid;
    if (fabsf(qq) < pivmin) qq = -pivmin;
    cnt += (qq < 0.f);
    for (int i = 1; i < NLS; ++i) {
      qq = d[i] - mid - e2[i - 1] / qq;
      if (fabsf(qq) < pivmin) qq = -pivmin;
      cnt += (qq < 0.f);
    }
    if (cnt > idx) hi = mid; else lo = mid;
  }
  float ev = 0.5f * (lo + hi);
  p.eigs[cloud * NLS + idx] = ev > 0.f ? ev : 0.f;
}

// ---------------- final ----------------
__global__ void final_kernel(Ptrs p, float* out) {
  __shared__ float lds[64];
  int tid = threadIdx.x;   // 256
  for (int cloud = 0; cloud < 2; ++cloud) {
    float num = 0.f, den = 0.f;
    for (int i = tid; i < NLS; i += 256) {
      float lam = p.eigs[cloud * NLS + i];
      float g = 1.f / (1.f + expf(-(lam - 1e-4f) * 100.f));
      num += lam * g;
      den += g;
    }
    for (int o = 32; o > 0; o >>= 1) {
      num += __shfl_down(num, o);
      den += __shfl_down(den, o);
    }
    if ((tid & 63) == 0) { lds[(tid >> 6) * 2] = num; lds[(tid >> 6) * 2 + 1] = den; }
    __syncthreads();
    if (tid == 0) {
      float N = lds[0] + lds[2] + lds[4] + lds[6];
      float D = lds[1] + lds[3] + lds[5] + lds[7];
      lds[32 + cloud] = N / (D + 1e-12f);
    }
    __syncthreads();
  }
  if (tid == 0) {
    float gp = lds[32], gn = lds[33];
    float trip = gp - gn + 0.5f;
    if (trip < 0.f) trip = 0.f;
    out[0] = trip + 0.1f * gp;
  }
}

extern "C" void kernel_launch(void* const* d_in, const int* in_sizes, int n_in,
                              void* d_out, int out_size, void* d_ws, size_t ws_size,
                              hipStream_t stream) {
  const float* q  = (const float*)d_in[0];
  const float* pe = (const float*)d_in[1];
  const float* ne = (const float*)d_in[2];
  const float* W  = (const float*)d_in[3];

  char* base = (char*)d_ws;
  size_t off = 0;
  auto alloc = [&](size_t nbytes) -> void* {
    off = (off + 255) & ~(size_t)255;
    void* r = base + off;
    off += nbytes;
    return r;
  };

  Ptrs p;
  p.X      = (float*)alloc(sizeof(float) * 2 * NNODE * SDIM);
  p.nn     = (int*)  alloc(sizeof(int)   * 2 * NNODE * KNN_K);
  p.nbr    = (int*)  alloc(sizeof(int)   * 2 * NNODE * MAXNBR);
  p.cnt    = (int*)  alloc(sizeof(int)   * 2 * NNODE);
  p.y      = (float*)alloc(sizeof(float) * 2 * 2 * NLS);
  p.acol   = (float*)alloc(sizeof(float) * 2 * NLS);
  p.darr   = (float*)alloc(sizeof(float) * 2 * NLS);
  p.ebuf   = (float*)alloc(sizeof(float) * 2 * NLS);
  p.bta    = (float*)alloc(sizeof(float) * 2 * NLS);
  p.e2     = (float*)alloc(sizeof(float) * 2 * NLS);
  p.bounds = (float*)alloc(sizeof(float) * 4);
  p.eigs   = (float*)alloc(sizeof(float) * 2 * NLS);
  p.Vt     = (float*)alloc(sizeof(float) * 2 * NB * NLS);
  p.Wt     = (float*)alloc(sizeof(float) * 2 * NB * NLS);
  p.c1     = (float*)alloc(sizeof(float) * 2 * NB);
  p.c2     = (float*)alloc(sizeof(float) * 2 * NB);

  // zero-initialized block (contiguous): vtw, xn2, bar, uctr
  size_t zstart = (off + 255) & ~(size_t)255;
  p.vtw    = (float*)alloc(sizeof(float) * 2 * NLS);
  p.xn2    = (float*)alloc(sizeof(float) * 2 * NLS);
  p.bar    = (int*)  alloc(sizeof(int)   * 2 * NLS * 2);
  p.uctr   = (int*)  alloc(sizeof(int)   * 2 * 128);
  size_t zend = off;
  long zcount = (long)((zend - zstart) / 4);

  const size_t Abytes = (size_t)NLS * NLS * sizeof(float);
  p.A0 = (float*)alloc(Abytes);
  size_t offA1 = (off + 255) & ~(size_t)255;
  bool batched = (offA1 + Abytes) <= ws_size;
  p.A1 = batched ? (float*)alloc(Abytes) : p.A0;

  // ---- shared preamble ----
  zero_kernel<<<dim3((int)((zcount + 255) / 256)), 256, 0, stream>>>((float*)(base + zstart), zcount);
  proj_kernel<<<dim3(32), 256, 0, stream>>>(p, q, pe, ne, W);
  knn_kernel<<<dim3(NNODE, 1, 2), 64, 0, stream>>>(p);
  adj_kernel<<<dim3(4), 256, 0, stream>>>(p);

  auto run_cloud = [&](int cloud0, int z) {
    assemble_kernel<<<dim3(NNODE, 1, z), 256, 0, stream>>>(p, cloud0);
    ka0_kernel<<<dim3(1, 1, z), 256, 0, stream>>>(p, cloud0);
    for (int k0 = 0; k0 + NB <= NLS - 64; k0 += NB) {
      for (int jj = 0; jj < NB; ++jj) {
        int k = k0 + jj;
        int m = NLS - k - 1;
        int Bt = (m + 127) / 128;
        int ntl = Bt * (Bt + 1) / 2;
        int G = ntl + jj;
        int Ge = (m + 255) / 256;
        if (Ge > G) G = Ge;
        if (G > 448) G = 448;
        if (G < 1) G = 1;
        col_kernel<<<dim3(G, 1, z), 256, 0, stream>>>(p, k, jj, cloud0);
      }
      int mp = NLS - (k0 + NB);
      int nt = (mp + 63) / 64;
      int doka = (k0 + 2 * NB <= NLS - 64) ? 1 : 0;
      kupd_kernel<<<dim3(nt, nt, z), 256, 0, stream>>>(p, k0, cloud0, doka, k0 / NB);
    }
    ktrail_kernel<<<dim3(1, 1, z), 64, 0, stream>>>(p, cloud0);
    gather_kernel<<<dim3(1, 1, z), 1024, 0, stream>>>(p, cloud0);
    bisect_kernel<<<dim3(NLS / 256, 1, z), 256, 0, stream>>>(p, cloud0);
  };

  if (batched) {
    run_cloud(0, 2);
  } else {
    run_cloud(0, 1);
    run_cloud(1, 1);
  }

  final_kernel<<<dim3(1), 256, 0, stream>>>(p, (float*)d_out);
}

// Round 4
// 185106.738 us; speedup vs baseline: 1.8860x; 1.8860x over previous
//
#include <hip/hip_runtime.h>
#include <math.h>

#define NLS    4096   // 512 nodes * 8 stalk dims
#define NNODE  512
#define SDIM   8
#define KNN_K  5
#define MAXNBR 128
#define DIN    768
#define NB     32     // panel width
#define GMAX   224    // max WGs per z-slice for col_kernel (co-residency safe)

#define AGLD(p)    __hip_atomic_load((p), __ATOMIC_RELAXED, __HIP_MEMORY_SCOPE_AGENT)
#define AGST(p, v) __hip_atomic_store((p), (v), __ATOMIC_RELAXED, __HIP_MEMORY_SCOPE_AGENT)

struct Ptrs {
  float* X;      // [2][NNODE][SDIM]
  int*   nn;     // [2][NNODE][KNN_K]
  int*   nbr;    // [2][NNODE][MAXNBR]
  int*   cnt;    // [2][NNODE]
  float* y;      // [2][NLS]   y = A_trail * v (stale), per column
  float* acol;   // [2][NLS]   corrected column k (valid r >= k)
  float* vtw;    // [2][NLS]   v^T y accumulators (zeroed at start)
  float* xn2;    // [2][NLS]   xnorm2 per column (zeroed at start)
  float* darr;   // [2][NLS]
  float* ebuf;   // [2][NLS]
  float* e2;     // [2][NLS]
  float* bounds; // [2][2]
  float* eigs;   // [2][NLS]
  float* Vt;     // [2][NB][NLS]
  float* Wt;     // [2][NB][NLS]
  float* c1;     // [2][NB]
  float* c2;     // [2][NB]
  int*   bar;    // [2][NLS]   grid-barrier counters (zeroed at start)
  int*   uctr;   // [2][128]   kupd last-WG counters (zeroed at start)
  float* A0;
  float* A1;
};

__device__ __forceinline__ float* matA(const Ptrs& p, int cloud) {
  return cloud == 0 ? p.A0 : p.A1;
}

// single-use grid barrier (counter pre-zeroed). Arrival: atomicAdd.
// Wait: agent-scope atomic LOAD (no RMW) with sleep backoff.
__device__ __forceinline__ void gbar(int* ctr, int total) {
  __syncthreads();
  if (threadIdx.x == 0) {
    __threadfence();                       // release: wb local L2
    atomicAdd(ctr, 1);
    while (AGLD(ctr) < total) __builtin_amdgcn_s_sleep(16);
    __threadfence();                       // acquire: inv stale lines
  }
  __syncthreads();
}

// ---------------- zero helper ----------------
__global__ void zero_kernel(float* ptr, long n) {
  long i = (long)blockIdx.x * 256 + threadIdx.x;
  if (i < n) ptr[i] = 0.f;
}

// ---------------- projection: X = emb @ W^T ----------------
__global__ void proj_kernel(Ptrs p, const float* q, const float* pe,
                            const float* ne, const float* W) {
  int idx = blockIdx.x * 256 + threadIdx.x;
  if (idx >= 2 * NNODE * SDIM) return;
  int cloud = idx >> 12;
  int rem   = idx & 4095;
  int node  = rem >> 3, t = rem & 7;
  const float* src = (node < 256) ? (q + (size_t)node * DIN)
                                  : ((cloud == 0 ? pe : ne) + (size_t)(node - 256) * DIN);
  const float* wr = W + (size_t)t * DIN;
  float acc = 0.f;
  for (int i = 0; i < DIN; ++i) acc += src[i] * wr[i];
  p.X[(cloud * NNODE + node) * SDIM + t] = acc;
}

// ---------------- KNN ----------------
__global__ void knn_kernel(Ptrs p) {
  int i = blockIdx.x, cloud = blockIdx.z;
  int lane = threadIdx.x;
  __shared__ float d2s[NNODE];
  const float* X = p.X + cloud * NNODE * SDIM;
  float xi[SDIM];
  for (int t = 0; t < SDIM; ++t) xi[t] = X[i * SDIM + t];
  for (int j = lane; j < NNODE; j += 64) {
    float s = 0.f;
    for (int t = 0; t < SDIM; ++t) { float d = xi[t] - X[j * SDIM + t]; s += d * d; }
    d2s[j] = (j == i) ? 3.4e38f : s;
  }
  __syncthreads();
  for (int r = 0; r < KNN_K; ++r) {
    float bv = 3.39e38f; int bi = NNODE;
    for (int j = lane; j < NNODE; j += 64) {
      float val = d2s[j];
      if (val < bv || (val == bv && j < bi)) { bv = val; bi = j; }
    }
    for (int o = 32; o > 0; o >>= 1) {
      float ov = __shfl_down(bv, o); int oi = __shfl_down(bi, o);
      if (ov < bv || (ov == bv && oi < bi)) { bv = ov; bi = oi; }
    }
    if (lane == 0) {
      p.nn[(cloud * NNODE + i) * KNN_K + r] = bi;
      d2s[bi] = 3.4e38f;
    }
    __syncthreads();
  }
}

// ---------------- symmetrized adjacency ----------------
__global__ void adj_kernel(Ptrs p) {
  int idx = blockIdx.x * 256 + threadIdx.x;
  if (idx >= 2 * NNODE) return;
  int cloud = idx >> 9, i = idx & 511;
  const int* nn = p.nn + cloud * NNODE * KNN_K;
  int c = 0;
  for (int j = 0; j < NNODE; ++j) {
    if (j == i) continue;
    bool e = false;
    for (int r = 0; r < KNN_K; ++r)
      if (nn[i * KNN_K + r] == j || nn[j * KNN_K + r] == i) e = true;
    if (e) { if (c < MAXNBR) p.nbr[(cloud * NNODE + i) * MAXNBR + c] = j; ++c; }
  }
  p.cnt[cloud * NNODE + i] = (c > MAXNBR ? MAXNBR : c);
}

// ---------------- dense assembly of L (full square) ----------------
__global__ void assemble_kernel(Ptrs p, int cloud0) {
  int i = blockIdx.x;
  int cloud = cloud0 + blockIdx.z;
  float* A = matA(p, cloud);
  const float* X = p.X + cloud * NNODE * SDIM;
  const int* nbr = p.nbr + (cloud * NNODE + i) * MAXNBR;
  int cnt = p.cnt[cloud * NNODE + i];
  int tid = threadIdx.x;

  for (int idx = tid; idx < SDIM * NLS; idx += 256) {
    int t = idx >> 12;
    int c = idx & 4095;
    A[(size_t)(i * SDIM + t) * NLS + c] = 0.f;
  }
  __shared__ float diag[64];
  __shared__ float xi[SDIM];
  if (tid < SDIM) xi[tid] = X[i * SDIM + tid];
  if (tid < 64)   diag[tid] = 0.f;
  __syncthreads();

  for (int s = 0; s < cnt; ++s) {
    int j = nbr[s];
    float d[SDIM], ss = 0.f;
    for (int t = 0; t < SDIM; ++t) { d[t] = X[j * SDIM + t] - xi[t]; ss += d[t] * d[t]; }
    float dn = sqrtf(ss) + 1e-12f;
    float alpha = dn < 1.f ? dn : 1.f;
    float inv = 1.f / dn;
    if (tid < 64) {
      int t = tid >> 3, t2 = tid & 7;
      float ut = d[t] * inv, ut2 = d[t2] * inv;
      A[(size_t)(i * SDIM + t) * NLS + j * SDIM + t2] =
          alpha * ut * ut2 - (t == t2 ? 1.f : 0.f);
      if (j < i) {
        float beta = 2.f * alpha - alpha * alpha;
        diag[tid] += beta * ut * ut2;
      }
    }
  }
  __syncthreads();
  if (tid < 64) {
    int t = tid >> 3, t2 = tid & 7;
    A[(size_t)(i * SDIM + t) * NLS + i * SDIM + t2] =
        (t == t2 ? (float)cnt : 0.f) - diag[tid];
  }
}

// ---------------- initial column prep (column 0): read row 0 (coalesced) ----------------
__global__ void ka0_kernel(Ptrs p, int cloud0) {
  int cloud = cloud0 + blockIdx.z;
  const float* A = matA(p, cloud);
  float* acol = p.acol + (size_t)cloud * NLS;
  int tid = threadIdx.x;
  float part = 0.f;
  for (int r = tid; r < NLS; r += 256) {
    float a = A[r];                      // row 0 == column 0
    acol[r] = a;
    if (r >= 2) part += a * a;
  }
  __shared__ float red[4];
  for (int o = 32; o > 0; o >>= 1) part += __shfl_down(part, o);
  if ((tid & 63) == 0) red[tid >> 6] = part;
  __syncthreads();
  if (tid == 0) p.xn2[cloud * NLS] = red[0] + red[1] + red[2] + red[3];
}

// ---------------- fused per-column kernel: GEMV + barrier + w/V/W + next col ----------------
__global__ __launch_bounds__(256, 4) void col_kernel(Ptrs p, int k, int j, int cloud0) {
  int cloud = cloud0 + blockIdx.z;
  float* A  = matA(p, cloud);
  float* Vt = p.Vt + (size_t)cloud * NB * NLS;
  float* Wt = p.Wt + (size_t)cloud * NB * NLS;
  float* yv = p.y + (size_t)cloud * NLS;
  float* acol = p.acol + (size_t)cloud * NLS;
  int tid = threadIdx.x, lane = tid & 63, wv = tid >> 6;
  const int s = k + 1;

  __shared__ __align__(16) float vlds[NLS + 4];
  __shared__ float c1s[NB], c2s[NB], vks[NB], wks[NB];
  __shared__ float red4[4];

  // ---- preamble: Householder scalars (redundant per WG) ----
  float xnorm2 = p.xn2[cloud * NLS + k];
  float alpha  = acol[s];
  float tau, scale;
  {
    float beta;
    if (xnorm2 > 0.f) {
      beta  = -copysignf(sqrtf(alpha * alpha + xnorm2), alpha);
      tau   = (beta - alpha) / beta;
      scale = 1.f / (alpha - beta);
    } else { beta = alpha; tau = 0.f; scale = 0.f; }
    if (blockIdx.x == 0 && tid == 0) {
      p.darr[cloud * NLS + k] = acol[k];
      p.ebuf[cloud * NLS + k] = beta;
    }
  }

  // ---- stage v into LDS, aligned to global index (vbase = s & ~3) ----
  const int vbase = s & ~3;
  const int vn = NLS - vbase;
  for (int i = tid; i < vn; i += 256) {
    int c = vbase + i;
    vlds[i] = (c < s) ? 0.f : ((c == s) ? 1.f : acol[c] * scale);
  }
  __syncthreads();

  // ---- phase 1: y[r] = A[r][vbase..] . v (float4), vty partials ----
  const int TW = gridDim.x * 4;
  const int gw = blockIdx.x * 4 + wv;
  float vtyloc = 0.f;
  for (int r = s + gw; r < NLS; r += TW) {
    const float* Ar = A + (size_t)r * NLS;
    float acc = 0.f;
    for (int c = vbase + (lane << 2); c < NLS; c += 256) {
      const float4 a4 = *(const float4*)(Ar + c);
      const float4 v4 = *(const float4*)(&vlds[c - vbase]);
      acc += a4.x * v4.x + a4.y * v4.y + a4.z * v4.z + a4.w * v4.w;
    }
    for (int o = 32; o > 0; o >>= 1) acc += __shfl_down(acc, o);
    if (lane == 0) {
      AGST(&yv[r], acc);
      vtyloc += vlds[r - vbase] * acc;
    }
  }
  if (lane == 0 && vtyloc != 0.f) atomicAdd(&p.vtw[cloud * NLS + k], vtyloc);

  // ---- c1/c2 panel dots: WG b < j computes c1[b], c2[b] ----
  if (blockIdx.x < (unsigned)j) {
    int j2 = blockIdx.x;
    float s1 = 0.f, s2 = 0.f;
    for (int r = s + tid; r < NLS; r += 256) {
      float v = vlds[r - vbase];
      s1 += Wt[(size_t)j2 * NLS + r] * v;
      s2 += Vt[(size_t)j2 * NLS + r] * v;
    }
    __shared__ float r1[4], r2[4];
    for (int o = 32; o > 0; o >>= 1) { s1 += __shfl_down(s1, o); s2 += __shfl_down(s2, o); }
    if (lane == 0) { r1[wv] = s1; r2[wv] = s2; }
    __syncthreads();
    if (tid == 0) {
      AGST(&p.c1[cloud * NB + j2], r1[0] + r1[1] + r1[2] + r1[3]);
      AGST(&p.c2[cloud * NB + j2], r2[0] + r2[1] + r2[2] + r2[3]);
    }
  }

  gbar(p.bar + (size_t)cloud * NLS + k, gridDim.x);

  // ---- phase 2: w formation, V/W write, next-column acol + xn2 ----
  if (tid < j) {
    c1s[tid] = AGLD(&p.c1[cloud * NB + tid]);
    c2s[tid] = AGLD(&p.c2[cloud * NB + tid]);
    vks[tid] = Vt[(size_t)tid * NLS + s];
    wks[tid] = Wt[(size_t)tid * NLS + s];
  }
  __syncthreads();
  float vty = AGLD(&p.vtw[cloud * NLS + k]);
  float dotc = 0.f, corrs = 0.f;
  for (int j2 = 0; j2 < j; ++j2) {
    dotc  += c1s[j2] * c2s[j2];
    corrs += vks[j2] * c1s[j2] + wks[j2] * c2s[j2];
  }
  float s2v = tau * (vty - 2.f * dotc);
  float ys  = AGLD(&yv[s]);
  float wfirst = tau * ys - tau * corrs - 0.5f * tau * s2v;   // v[s] = 1
  bool havenext = (j < NB - 1);
  const float* Arow = A + (size_t)s * NLS;                    // next col s via row s
  float xpart = 0.f;
  for (int r = s + (blockIdx.x << 8) + tid; r < NLS; r += (gridDim.x << 8)) {
    float vr = vlds[r - vbase];
    float yr = AGLD(&yv[r]);
    float corr = 0.f, ac2 = 0.f;
    for (int j2 = 0; j2 < j; ++j2) {
      float vj = Vt[(size_t)j2 * NLS + r], wj = Wt[(size_t)j2 * NLS + r];
      corr += vj * c1s[j2] + wj * c2s[j2];
      ac2  += vj * wks[j2] + wj * vks[j2];
    }
    float wr = tau * yr - tau * corr - 0.5f * tau * s2v * vr;
    Vt[(size_t)j * NLS + r] = vr;
    Wt[(size_t)j * NLS + r] = wr;
    if (havenext) {
      float ac = Arow[r] - ac2 - (vr * wfirst + wr);
      acol[r] = ac;
      if (r >= s + 2) xpart += ac * ac;
    }
  }
  if (havenext) {
    for (int o = 32; o > 0; o >>= 1) xpart += __shfl_down(xpart, o);
    if (lane == 0) red4[wv] = xpart;
    __syncthreads();
    if (tid == 0) {
      float t = red4[0] + red4[1] + red4[2] + red4[3];
      if (t != 0.f) atomicAdd(&p.xn2[cloud * NLS + k + 1], t);
    }
  }
}

// ---------------- KUPD: full-square rank-2*NB update + next-panel col prep ----------------
__global__ void kupd_kernel(Ptrs p, int k0, int cloud0, int doka, int pidx) {
  int cloud = cloud0 + blockIdx.z;
  float* A = matA(p, cloud);
  const float* Vt = p.Vt + (size_t)cloud * NB * NLS;
  const float* Wt = p.Wt + (size_t)cloud * NB * NLS;
  int base = k0 + NB;
  int tid = threadIdx.x;
  __shared__ float Vr[NB][64], Wr[NB][64], Vc[NB][64], Wc[NB][64];
  __shared__ int lastFlag;
  __shared__ float red[4];

  {
    int r0 = base + blockIdx.y * 64, c0 = base + blockIdx.x * 64;
    for (int idx = tid; idx < NB * 64; idx += 256) {
      int jj = idx >> 6, i = idx & 63;
      int r = r0 + i, c = c0 + i;
      Vr[jj][i] = (r < NLS) ? Vt[(size_t)jj * NLS + r] : 0.f;
      Wr[jj][i] = (r < NLS) ? Wt[(size_t)jj * NLS + r] : 0.f;
      Vc[jj][i] = (c < NLS) ? Vt[(size_t)jj * NLS + c] : 0.f;
      Wc[jj][i] = (c < NLS) ? Wt[(size_t)jj * NLS + c] : 0.f;
    }
    __syncthreads();
    int ty = tid >> 4, tx = tid & 15;
    float acc[4][4] = {{0.f}};
    for (int jj = 0; jj < NB; ++jj) {
      float vr[4], wr[4], vc[4], wc[4];
      for (int a = 0; a < 4; ++a) {
        vr[a] = Vr[jj][ty * 4 + a]; wr[a] = Wr[jj][ty * 4 + a];
        vc[a] = Vc[jj][tx * 4 + a]; wc[a] = Wc[jj][tx * 4 + a];
      }
      for (int a = 0; a < 4; ++a)
        for (int b = 0; b < 4; ++b)
          acc[a][b] += vr[a] * wc[b] + wr[a] * vc[b];
    }
    for (int a = 0; a < 4; ++a) {
      int r = r0 + ty * 4 + a;
      int c = c0 + tx * 4;
      if (r < NLS && c < NLS) {
        float4* pa = (float4*)&A[(size_t)r * NLS + c];
        float4 old = *pa;
        old.x -= acc[a][0]; old.y -= acc[a][1];
        old.z -= acc[a][2]; old.w -= acc[a][3];
        *pa = old;
      }
    }
  }

  // last-WG: prepare first column of next panel (coalesced row read)
  if (tid == 0) {
    __threadfence();
    int tot = gridDim.x * gridDim.y;
    int old = atomicAdd(&p.uctr[cloud * 128 + pidx], 1);
    lastFlag = (old == tot - 1) ? 1 : 0;
  }
  __syncthreads();
  if (lastFlag && doka) {
    __threadfence();
    int kn = k0 + NB;
    float* acol = p.acol + (size_t)cloud * NLS;
    const float* Arow = A + (size_t)kn * NLS;
    float part = 0.f;
    for (int r = kn + tid; r < NLS; r += 256) {
      float a = Arow[r];
      acol[r] = a;
      if (r >= kn + 2) part += a * a;
    }
    for (int o = 32; o > 0; o >>= 1) part += __shfl_down(part, o);
    if ((tid & 63) == 0) red[tid >> 6] = part;
    __syncthreads();
    if (tid == 0) p.xn2[cloud * NLS + kn] = red[0] + red[1] + red[2] + red[3];
  }
}

// ---------------- trailing 64x64 block: in-LDS tridiagonalization ----------------
__global__ void ktrail_kernel(Ptrs p, int cloud0) {
  int cloud = cloud0 + blockIdx.z;
  float* A = matA(p, cloud);
  const int base = NLS - 64;
  int lane = threadIdx.x;  // 64 threads
  __shared__ float B[64][65];
  __shared__ float vv[64], ww[64];
  for (int r = 0; r < 64; ++r)
    B[r][lane] = A[(size_t)(base + r) * NLS + base + lane];
  __syncthreads();
  for (int kl = 0; kl <= 61; ++kl) {
    float val = (lane >= kl + 2) ? B[kl][lane] : 0.f;
    float part = val * val;
    for (int o = 32; o > 0; o >>= 1) part += __shfl_xor(part, o);
    float xnorm2 = part;
    float alpha = B[kl][kl + 1];
    float beta, tau, scale;
    if (xnorm2 > 0.f) {
      beta  = -copysignf(sqrtf(alpha * alpha + xnorm2), alpha);
      tau   = (beta - alpha) / beta;
      scale = 1.f / (alpha - beta);
    } else { beta = alpha; tau = 0.f; scale = 0.f; }
    if (lane == 0) {
      p.darr[cloud * NLS + base + kl] = B[kl][kl];
      p.ebuf[cloud * NLS + base + kl] = beta;
    }
    vv[lane] = (lane == kl + 1) ? 1.f : ((lane >= kl + 2) ? B[kl][lane] * scale : 0.f);
    __syncthreads();
    float yv = 0.f;
    if (lane >= kl + 1)
      for (int c = kl + 1; c < 64; ++c) yv += B[lane][c] * vv[c];
    float vy = (lane >= kl + 1) ? vv[lane] * yv : 0.f;
    for (int o = 32; o > 0; o >>= 1) vy += __shfl_xor(vy, o);
    float w = tau * yv - 0.5f * tau * (tau * vy) * vv[lane];
    ww[lane] = (lane >= kl + 1) ? w : 0.f;
    __syncthreads();
    if (lane >= kl + 1) {
      float vr = vv[lane], wr = ww[lane];
      for (int c = kl + 1; c < 64; ++c)
        B[lane][c] -= vr * ww[c] + wr * vv[c];
    }
    __syncthreads();
  }
  if (lane == 0) {
    p.darr[cloud * NLS + base + 62] = B[62][62];
    p.darr[cloud * NLS + base + 63] = B[63][63];
    p.ebuf[cloud * NLS + base + 62] = B[63][62];
    p.ebuf[cloud * NLS + base + 63] = 0.f;
  }
}

// ---------------- gather tridiagonal + Gershgorin bounds ----------------
__global__ void gather_kernel(Ptrs p, int cloud0) {
  int cloud = cloud0 + blockIdx.z;
  const int n = NLS;
  int tid = threadIdx.x;   // 1024
  const float* d = p.darr + cloud * NLS;
  float* e2 = p.e2 + cloud * NLS;
  __shared__ float elds[NLS];
  for (int i = tid; i < n; i += 1024) {
    float e = (i < n - 1) ? p.ebuf[cloud * NLS + i] : 0.f;
    e2[i]   = e * e;
    elds[i] = fabsf(e);
  }
  __syncthreads();
  float lo = 3.4e38f, hi = -3.4e38f;
  for (int i = tid; i < n; i += 1024) {
    float rad = elds[i] + (i > 0 ? elds[i - 1] : 0.f);
    lo = fminf(lo, d[i] - rad);
    hi = fmaxf(hi, d[i] + rad);
  }
  __shared__ float rl[16], rh[16];
  int lane = tid & 63, wv = tid >> 6;
  for (int o = 32; o > 0; o >>= 1) {
    lo = fminf(lo, __shfl_down(lo, o));
    hi = fmaxf(hi, __shfl_down(hi, o));
  }
  if (lane == 0) { rl[wv] = lo; rh[wv] = hi; }
  __syncthreads();
  if (tid == 0) {
    for (int t = 1; t < 16; ++t) { lo = fminf(lo, rl[t]); hi = fmaxf(hi, rh[t]); }
    p.bounds[cloud * 2 + 0] = lo - 0.5f;
    p.bounds[cloud * 2 + 1] = hi + 0.5f;
  }
}

// ---------------- bisection ----------------
__global__ void bisect_kernel(Ptrs p, int cloud0) {
  int cloud = cloud0 + blockIdx.z;
  int idx = blockIdx.x * 256 + threadIdx.x;
  const float* d  = p.darr + cloud * NLS;
  const float* e2 = p.e2   + cloud * NLS;
  float lo = p.bounds[cloud * 2 + 0];
  float hi = p.bounds[cloud * 2 + 1];
  const float pivmin = 1e-28f;
  for (int it = 0; it < 34; ++it) {
    float mid = 0.5f * (lo + hi);
    int cnt = 0;
    float qq = d[0] - mid;
    if (fabsf(qq) < pivmin) qq = -pivmin;
    cnt += (qq < 0.f);
    for (int i = 1; i < NLS; ++i) {
      qq = d[i] - mid - e2[i - 1] / qq;
      if (fabsf(qq) < pivmin) qq = -pivmin;
      cnt += (qq < 0.f);
    }
    if (cnt > idx) hi = mid; else lo = mid;
  }
  float ev = 0.5f * (lo + hi);
  p.eigs[cloud * NLS + idx] = ev > 0.f ? ev : 0.f;
}

// ---------------- final ----------------
__global__ void final_kernel(Ptrs p, float* out) {
  __shared__ float lds[64];
  int tid = threadIdx.x;   // 256
  for (int cloud = 0; cloud < 2; ++cloud) {
    float num = 0.f, den = 0.f;
    for (int i = tid; i < NLS; i += 256) {
      float lam = p.eigs[cloud * NLS + i];
      float g = 1.f / (1.f + expf(-(lam - 1e-4f) * 100.f));
      num += lam * g;
      den += g;
    }
    for (int o = 32; o > 0; o >>= 1) {
      num += __shfl_down(num, o);
      den += __shfl_down(den, o);
    }
    if ((tid & 63) == 0) { lds[(tid >> 6) * 2] = num; lds[(tid >> 6) * 2 + 1] = den; }
    __syncthreads();
    if (tid == 0) {
      float N = lds[0] + lds[2] + lds[4] + lds[6];
      float D = lds[1] + lds[3] + lds[5] + lds[7];
      lds[32 + cloud] = N / (D + 1e-12f);
    }
    __syncthreads();
  }
  if (tid == 0) {
    float gp = lds[32], gn = lds[33];
    float trip = gp - gn + 0.5f;
    if (trip < 0.f) trip = 0.f;
    out[0] = trip + 0.1f * gp;
  }
}

extern "C" void kernel_launch(void* const* d_in, const int* in_sizes, int n_in,
                              void* d_out, int out_size, void* d_ws, size_t ws_size,
                              hipStream_t stream) {
  const float* q  = (const float*)d_in[0];
  const float* pe = (const float*)d_in[1];
  const float* ne = (const float*)d_in[2];
  const float* W  = (const float*)d_in[3];

  char* base = (char*)d_ws;
  size_t off = 0;
  auto alloc = [&](size_t nbytes) -> void* {
    off = (off + 255) & ~(size_t)255;
    void* r = base + off;
    off += nbytes;
    return r;
  };

  Ptrs p;
  p.X      = (float*)alloc(sizeof(float) * 2 * NNODE * SDIM);
  p.nn     = (int*)  alloc(sizeof(int)   * 2 * NNODE * KNN_K);
  p.nbr    = (int*)  alloc(sizeof(int)   * 2 * NNODE * MAXNBR);
  p.cnt    = (int*)  alloc(sizeof(int)   * 2 * NNODE);
  p.y      = (float*)alloc(sizeof(float) * 2 * NLS);
  p.acol   = (float*)alloc(sizeof(float) * 2 * NLS);
  p.darr   = (float*)alloc(sizeof(float) * 2 * NLS);
  p.ebuf   = (float*)alloc(sizeof(float) * 2 * NLS);
  p.e2     = (float*)alloc(sizeof(float) * 2 * NLS);
  p.bounds = (float*)alloc(sizeof(float) * 4);
  p.eigs   = (float*)alloc(sizeof(float) * 2 * NLS);
  p.Vt     = (float*)alloc(sizeof(float) * 2 * NB * NLS);
  p.Wt     = (float*)alloc(sizeof(float) * 2 * NB * NLS);
  p.c1     = (float*)alloc(sizeof(float) * 2 * NB);
  p.c2     = (float*)alloc(sizeof(float) * 2 * NB);

  // zero-initialized block (contiguous): vtw, xn2, bar, uctr
  size_t zstart = (off + 255) & ~(size_t)255;
  p.vtw    = (float*)alloc(sizeof(float) * 2 * NLS);
  p.xn2    = (float*)alloc(sizeof(float) * 2 * NLS);
  p.bar    = (int*)  alloc(sizeof(int)   * 2 * NLS);
  p.uctr   = (int*)  alloc(sizeof(int)   * 2 * 128);
  size_t zend = off;
  long zcount = (long)((zend - zstart) / 4);

  const size_t Abytes = (size_t)NLS * NLS * sizeof(float);
  p.A0 = (float*)alloc(Abytes);
  size_t offA1 = (off + 255) & ~(size_t)255;
  bool batched = (offA1 + Abytes) <= ws_size;
  p.A1 = batched ? (float*)alloc(Abytes) : p.A0;

  // ---- shared preamble ----
  zero_kernel<<<dim3((int)((zcount + 255) / 256)), 256, 0, stream>>>((float*)(base + zstart), zcount);
  proj_kernel<<<dim3(32), 256, 0, stream>>>(p, q, pe, ne, W);
  knn_kernel<<<dim3(NNODE, 1, 2), 64, 0, stream>>>(p);
  adj_kernel<<<dim3(4), 256, 0, stream>>>(p);

  auto run_cloud = [&](int cloud0, int z) {
    assemble_kernel<<<dim3(NNODE, 1, z), 256, 0, stream>>>(p, cloud0);
    ka0_kernel<<<dim3(1, 1, z), 256, 0, stream>>>(p, cloud0);
    for (int k0 = 0; k0 + NB <= NLS - 64; k0 += NB) {
      for (int jj = 0; jj < NB; ++jj) {
        int k = k0 + jj;
        int m = NLS - k - 1;
        int G = (m + 15) / 16;
        if (G < 32)   G = 32;
        if (G > GMAX) G = GMAX;
        col_kernel<<<dim3(G, 1, z), 256, 0, stream>>>(p, k, jj, cloud0);
      }
      int mp = NLS - (k0 + NB);
      int nt = (mp + 63) / 64;
      int doka = (k0 + 2 * NB <= NLS - 64) ? 1 : 0;
      kupd_kernel<<<dim3(nt, nt, z), 256, 0, stream>>>(p, k0, cloud0, doka, k0 / NB);
    }
    ktrail_kernel<<<dim3(1, 1, z), 64, 0, stream>>>(p, cloud0);
    gather_kernel<<<dim3(1, 1, z), 1024, 0, stream>>>(p, cloud0);
    bisect_kernel<<<dim3(NLS / 256, 1, z), 256, 0, stream>>>(p, cloud0);
  };

  if (batched) {
    run_cloud(0, 2);
  } else {
    run_cloud(0, 1);
    run_cloud(1, 1);
  }

  final_kernel<<<dim3(1), 256, 0, stream>>>(p, (float*)d_out);
}